// Round 3
// baseline (664.802 us; speedup 1.0000x reference)
//
#include <hip/hip_runtime.h>
#include <hip/hip_bf16.h>
#include <cstdint>

constexpr int B_    = 4;
constexpr int NIN_  = 50000;
constexpr int NOUT_ = 50000;
constexpr int E_    = 819200;
constexpr int CI    = 16;
constexpr int CO    = 16;
constexpr int Hh    = 100;

constexpr int TILE = 64;     // edges per block
constexpr int KP   = 128;    // padded hidden dim

typedef __attribute__((ext_vector_type(8))) short bf16x8;
typedef __attribute__((ext_vector_type(4))) float f32x4;

__device__ inline unsigned short f2bf(float f) {
    __hip_bfloat16 h = __float2bfloat16(f);   // compiler emits native cvt (m240)
    return *reinterpret_cast<unsigned short*>(&h);
}
__host__ inline unsigned short f2bf_h(float f) {
    union { float f; unsigned u; } v; v.f = f;
    unsigned r = v.u + 0x7FFF + ((v.u >> 16) & 1);
    return (unsigned short)(r >> 16);
}

// chunk-level (16B) XOR swizzle within a 128-bf16 row
__device__ inline int swz(int r, int k) {
    return r * KP + (k ^ (((r & 7) << 3) ^ ((r & 8) << 1)));
}

// ---------------- prep: padded transposed bf16 weights + padded biases ------
__global__ __launch_bounds__(256)
void prep_kernel(const float* __restrict__ w2, const float* __restrict__ w3,
                 const float* __restrict__ w4, const float* __restrict__ b2,
                 const float* __restrict__ b3, const float* __restrict__ b4,
                 unsigned short* __restrict__ W2T, unsigned short* __restrict__ W3T,
                 unsigned short* __restrict__ W4T,
                 float* __restrict__ b2p, float* __restrict__ b3p,
                 float* __restrict__ b4p)
{
    int i = blockIdx.x * 256 + threadIdx.x;
    auto cvt = [](float f) {
        __hip_bfloat16 h = __float2bfloat16(f);
        return *reinterpret_cast<unsigned short*>(&h);
    };
    if (i < 16384) {                       // W2T[n][k] = w2[k][n], 128x128
        int n = i >> 7, k = i & 127;
        W2T[i] = (n < Hh && k < Hh) ? cvt(w2[k * Hh + n]) : (unsigned short)0;
    } else if (i < 32768) {                // W3T
        int j = i - 16384; int n = j >> 7, k = j & 127;
        W3T[j] = (n < Hh && k < Hh) ? cvt(w3[k * Hh + n]) : (unsigned short)0;
    } else if (i < 65536) {                // W4T[n][k] = w4[k][n], 256x128
        int j = i - 32768; int n = j >> 7, k = j & 127;
        W4T[j] = (k < Hh) ? cvt(w4[k * 256 + n]) : (unsigned short)0;
    } else if (i < 65664) {
        int j = i - 65536; b2p[j] = (j < Hh) ? b2[j] : 0.f;
    } else if (i < 65792) {
        int j = i - 65664; b3p[j] = (j < Hh) ? b3[j] : 0.f;
    } else if (i < 66048) {
        int j = i - 65792; b4p[j] = b4[j];
    }
}

// ---------------- MFMA hidden layer (relu(src @ W + b)) --------------------
__device__ inline void mfma_layer(const unsigned short* __restrict__ WT,
                                  const float* __restrict__ bp,
                                  const unsigned short* __restrict__ src,
                                  unsigned short* __restrict__ dst,
                                  int wv, int lane)
{
    const int cl = lane & 15;
    const int kg = lane >> 4;
    #pragma unroll
    for (int t = 0; t < 2; ++t) {
        const int nt = wv * 2 + t;
        const unsigned short* wrow = WT + (nt * 16 + cl) * KP + kg * 8;
        bf16x8 bf[4];
        #pragma unroll
        for (int ks = 0; ks < 4; ++ks)
            bf[ks] = *reinterpret_cast<const bf16x8*>(wrow + ks * 32);
        const float bv = bp[nt * 16 + cl];
        #pragma unroll
        for (int mt = 0; mt < 4; ++mt) {
            f32x4 acc = {bv, bv, bv, bv};
            const int row = mt * 16 + cl;
            #pragma unroll
            for (int ks = 0; ks < 4; ++ks) {
                bf16x8 af = *reinterpret_cast<const bf16x8*>(
                    &src[swz(row, ks * 32 + kg * 8)]);
                acc = __builtin_amdgcn_mfma_f32_16x16x32_bf16(af, bf[ks], acc, 0, 0, 0);
            }
            #pragma unroll
            for (int j = 0; j < 4; ++j)
                dst[swz(mt * 16 + kg * 4 + j, nt * 16 + cl)] =
                    f2bf(fmaxf(acc[j], 0.f));
        }
    }
}

// ---------------- main fused kernel ----------------------------------------
__global__ __launch_bounds__(256, 4)
void edge_kernel(const float* __restrict__ x, const float* __restrict__ ipos,
                 const float* __restrict__ opos, const int* __restrict__ esrc,
                 const int* __restrict__ edst,
                 const float* __restrict__ w1, const float* __restrict__ b1,
                 const unsigned short* __restrict__ W2T,
                 const unsigned short* __restrict__ W3T,
                 const unsigned short* __restrict__ W4T,
                 const float* __restrict__ b2p, const float* __restrict__ b3p,
                 const float* __restrict__ b4p,
                 float* __restrict__ agg, float* __restrict__ deg)
{
    __shared__ unsigned short hA[TILE * KP];   // 16 KB: h1, h3
    __shared__ unsigned short hB[TILE * KP];   // 16 KB: h2, then xs[16][64] float4
    __shared__ float s_attr[TILE * 9];         // 2.3 KB
    __shared__ int s_src[TILE], s_dst[TILE];

    const int tid  = threadIdx.x;
    const int wv   = __builtin_amdgcn_readfirstlane(tid >> 6);
    const int lane = tid & 63;
    const int e0   = blockIdx.x * TILE;

    if (tid < TILE) {
        int s = esrc[e0 + tid];
        int d = edst[e0 + tid];
        s_src[tid] = s; s_dst[tid] = d;
        s_attr[tid * 9 + 0] = opos[d * 3 + 0];
        s_attr[tid * 9 + 1] = opos[d * 3 + 1];
        s_attr[tid * 9 + 2] = opos[d * 3 + 2];
        s_attr[tid * 9 + 3] = ipos[s * 3 + 0];
        s_attr[tid * 9 + 4] = ipos[s * 3 + 1];
        s_attr[tid * 9 + 5] = ipos[s * 3 + 2];
        atomicAdd(&deg[d], 1.0f);
    }
    __syncthreads();

    // ---- layer 1 (fp32 VALU, K=6): attr -> hA ----
    {
        float acc1[32];
        const int c0 = wv * 32;
        #pragma unroll
        for (int cc = 0; cc < 32; ++cc) {
            int c = c0 + cc;
            acc1[cc] = (c < Hh) ? b1[c] : 0.f;
        }
        #pragma unroll
        for (int k = 0; k < 6; ++k) {
            float a = s_attr[lane * 9 + k];
            #pragma unroll
            for (int cc = 0; cc < 32; ++cc) {
                int c = c0 + cc;
                float w = (c < Hh) ? w1[k * Hh + c] : 0.f;   // wave-uniform -> s_load
                acc1[cc] = fmaf(a, w, acc1[cc]);
            }
        }
        #pragma unroll
        for (int cc = 0; cc < 32; cc += 2) {
            unsigned lo = f2bf(fmaxf(acc1[cc], 0.f));
            unsigned hi = f2bf(fmaxf(acc1[cc + 1], 0.f));
            *reinterpret_cast<unsigned*>(&hA[swz(lane, c0 + cc)]) = lo | (hi << 16);
        }
    }
    __syncthreads();

    mfma_layer(W2T, b2p, hA, hB, wv, lane);    // h1 -> h2
    __syncthreads();

    // ---- T14 async gather: issue x loads now; LDS-write after layer 3 ----
    // thread (wv, lane): edge e=lane, i-quad q0=wv*4; loads x[b][src][q0..q0+3]
    float4 xg[4];
    {
        const int src = s_src[lane];
        #pragma unroll
        for (int b = 0; b < 4; ++b)
            xg[b] = *reinterpret_cast<const float4*>(
                &x[((size_t)b * NIN_ + src) * CI + wv * 4]);
    }

    mfma_layer(W3T, b3p, hB, hA, wv, lane);    // h2 -> h3
    __syncthreads();                            // hB (h2) now dead

    // ---- write xs[i][e] float4 over b: 64-lane contiguous, conflict-free ----
    float4* xs4 = reinterpret_cast<float4*>(hB);   // [16][64] float4
    {
        #pragma unroll
        for (int q = 0; q < 4; ++q) {
            float4 v;
            v.x = xg[0][q]; v.y = xg[1][q]; v.z = xg[2][q]; v.w = xg[3][q];
            xs4[(wv * 4 + q) * 64 + lane] = v;
        }
    }

    // A-frags for layer 4 (h3 rows = this wave's 16 edges)
    const int cl = lane & 15;
    const int kg = lane >> 4;
    bf16x8 af4[4];
    {
        const int row = wv * 16 + cl;
        #pragma unroll
        for (int ks = 0; ks < 4; ++ks)
            af4[ks] = *reinterpret_cast<const bf16x8*>(
                &hA[swz(row, ks * 32 + kg * 8)]);
    }
    __syncthreads();                            // xs visible to all

    // ---- layer 4 + fused message ----
    float macc[16];   // [b*4 + j]
    #pragma unroll
    for (int q = 0; q < 16; ++q) macc[q] = 0.f;

    #pragma unroll 4
    for (int nt = 0; nt < 16; ++nt) {
        const unsigned short* wrow = W4T + (nt * 16 + cl) * KP + kg * 8;
        const float bv = b4p[nt * 16 + cl];
        f32x4 acc = {bv, bv, bv, bv};
        #pragma unroll
        for (int ks = 0; ks < 4; ++ks) {
            bf16x8 bfr = *reinterpret_cast<const bf16x8*>(wrow + ks * 32);
            acc = __builtin_amdgcn_mfma_f32_16x16x32_bf16(af4[ks], bfr, acc, 0, 0, 0);
        }
        #pragma unroll
        for (int j = 0; j < 4; ++j) {
            const int e = wv * 16 + kg * 4 + j;
            float4 xv = xs4[nt * 64 + e];       // ds_read_b128, broadcast/2-way
            macc[0 * 4 + j] = fmaf(xv.x, acc[j], macc[0 * 4 + j]);
            macc[1 * 4 + j] = fmaf(xv.y, acc[j], macc[1 * 4 + j]);
            macc[2 * 4 + j] = fmaf(xv.z, acc[j], macc[2 * 4 + j]);
            macc[3 * 4 + j] = fmaf(xv.w, acc[j], macc[3 * 4 + j]);
        }
    }

    // ---- scatter ----
    #pragma unroll
    for (int j = 0; j < 4; ++j) {
        const int e = wv * 16 + kg * 4 + j;
        float* p = agg + (size_t)s_dst[e] * (B_ * CO) + cl;
        #pragma unroll
        for (int b = 0; b < 4; ++b)
            atomicAdd(p + b * 16, macc[b * 4 + j]);
    }
}

// out[b][n][o] = agg[n][b][o] / max(deg[n],1) + bias[o]
__global__ __launch_bounds__(256)
void finalize_kernel(const float* __restrict__ agg, const float* __restrict__ deg,
                     const float* __restrict__ bias, float* __restrict__ out)
{
    const int idx = blockIdx.x * 256 + threadIdx.x;
    if (idx >= B_ * NOUT_ * CO) return;
    const int o = idx & 15;
    const int n = (idx >> 4) % NOUT_;
    const int b = idx / (NOUT_ * CO);
    const float d = fmaxf(deg[n], 1.0f);
    out[idx] = agg[(size_t)n * (B_ * CO) + b * CO + o] / d + bias[o];
}

extern "C" void kernel_launch(void* const* d_in, const int* in_sizes, int n_in,
                              void* d_out, int out_size, void* d_ws, size_t ws_size,
                              hipStream_t stream)
{
    const float* x    = (const float*)d_in[0];
    const float* ipos = (const float*)d_in[1];
    const float* opos = (const float*)d_in[2];
    const int*   esrc = (const int*)d_in[3];
    const int*   edst = (const int*)d_in[4];
    const float* w1   = (const float*)d_in[5];
    const float* b1   = (const float*)d_in[6];
    const float* w2   = (const float*)d_in[7];
    const float* b2   = (const float*)d_in[8];
    const float* w3   = (const float*)d_in[9];
    const float* b3   = (const float*)d_in[10];
    const float* w4   = (const float*)d_in[11];
    const float* b4   = (const float*)d_in[12];
    const float* bias = (const float*)d_in[14];

    // Scratch weights in d_out's first 133 KB; finalize overwrites them.
    char* ob = (char*)d_out;
    unsigned short* W2T = (unsigned short*)(ob);            // 32 KB
    unsigned short* W3T = (unsigned short*)(ob + 32768);    // 32 KB
    unsigned short* W4T = (unsigned short*)(ob + 65536);    // 64 KB
    float* b2p = (float*)(ob + 131072);
    float* b3p = (float*)(ob + 131584);
    float* b4p = (float*)(ob + 132096);

    float* agg = (float*)d_ws;
    float* deg = agg + (size_t)NOUT_ * (B_ * CO);

    hipMemsetAsync(d_ws, 0,
                   ((size_t)NOUT_ * (B_ * CO) + NOUT_) * sizeof(float), stream);

    prep_kernel<<<258, 256, 0, stream>>>(w2, w3, w4, b2, b3, b4,
                                         W2T, W3T, W4T, b2p, b3p, b4p);

    edge_kernel<<<E_ / TILE, 256, 0, stream>>>(
        x, ipos, opos, esrc, edst, w1, b1,
        W2T, W3T, W4T, b2p, b3p, b4p, agg, deg);

    const int total = B_ * NOUT_ * CO;
    finalize_kernel<<<(total + 255) / 256, 256, 0, stream>>>(agg, deg, bias,
                                                             (float*)d_out);
}

// Round 4
// 583.516 us; speedup vs baseline: 1.1393x; 1.1393x over previous
//
#include <hip/hip_runtime.h>
#include <hip/hip_bf16.h>
#include <cstdint>

constexpr int B_    = 4;
constexpr int NIN_  = 50000;
constexpr int NOUT_ = 50000;
constexpr int E_    = 819200;
constexpr int CI    = 16;
constexpr int CO    = 16;
constexpr int Hh    = 100;

constexpr int M    = 32;     // edges per wave-tile (wave-private, no barriers)
constexpr int KP   = 128;    // padded hidden dim
constexpr int XSS  = 38;     // xs row stride in float4 (padded, 0-conflict reads)

typedef __attribute__((ext_vector_type(8))) short bf16x8;
typedef __attribute__((ext_vector_type(4))) float f32x4;

__device__ inline unsigned short f2bf(float f) {
    __hip_bfloat16 h = __float2bfloat16(f);
    return *reinterpret_cast<unsigned short*>(&h);
}

// chunk-level (16B) XOR swizzle within a 128-bf16 row (verified rounds 2-3)
__device__ inline int swz(int r, int k) {
    return r * KP + (k ^ (((r & 7) << 3) ^ ((r & 8) << 1)));
}
// xs edge-index map: groups of 8 edges + 2-float4 pad -> kg-groups land on
// disjoint bank quartets during message reads (0-conflict)
__device__ inline int exmap(int e) { return e + 2 * (e >> 3); }

// ---------------- prep: padded transposed bf16 weights + padded biases ------
__global__ __launch_bounds__(256)
void prep_kernel(const float* __restrict__ w1, const float* __restrict__ w2,
                 const float* __restrict__ w3, const float* __restrict__ w4,
                 const float* __restrict__ b1, const float* __restrict__ b2,
                 const float* __restrict__ b3, const float* __restrict__ b4,
                 unsigned short* __restrict__ W1T, unsigned short* __restrict__ W2T,
                 unsigned short* __restrict__ W3T, unsigned short* __restrict__ W4T,
                 float* __restrict__ b1p, float* __restrict__ b2p,
                 float* __restrict__ b3p, float* __restrict__ b4p)
{
    int i = blockIdx.x * 256 + threadIdx.x;
    auto cvt = [](float f) {
        __hip_bfloat16 h = __float2bfloat16(f);
        return *reinterpret_cast<unsigned short*>(&h);
    };
    if (i < 16384) {                       // W2T[n][k] = w2[k][n], 128x128
        int n = i >> 7, k = i & 127;
        W2T[i] = (n < Hh && k < Hh) ? cvt(w2[k * Hh + n]) : (unsigned short)0;
    } else if (i < 32768) {                // W3T
        int j = i - 16384; int n = j >> 7, k = j & 127;
        W3T[j] = (n < Hh && k < Hh) ? cvt(w3[k * Hh + n]) : (unsigned short)0;
    } else if (i < 65536) {                // W4T[n][k] = w4[k][n], 256x128
        int j = i - 32768; int n = j >> 7, k = j & 127;
        W4T[j] = (k < Hh) ? cvt(w4[k * 256 + n]) : (unsigned short)0;
    } else if (i < 69632) {                // W1T[c][k] = w1[k][c], 128x32
        int j = i - 65536; int c = j >> 5, k = j & 31;
        W1T[j] = (k < 6 && c < Hh) ? cvt(w1[k * Hh + c]) : (unsigned short)0;
    } else if (i < 69760) {
        int j = i - 69632; b1p[j] = (j < Hh) ? b1[j] : 0.f;
    } else if (i < 69888) {
        int j = i - 69760; b2p[j] = (j < Hh) ? b2[j] : 0.f;
    } else if (i < 70016) {
        int j = i - 69888; b3p[j] = (j < Hh) ? b3[j] : 0.f;
    } else if (i < 70272) {
        int j = i - 70016; b4p[j] = b4[j];
    }
}

// ---- hidden layer: hb <- relu(hb @ WT^T + b), in place, wave-private ------
// A-frags all read up-front (in-place safe); B streamed from L2.
__device__ inline void hidden_layer(const unsigned short* __restrict__ WT,
                                    const float* __restrict__ bp,
                                    short* hb, int cl, int kg)
{
    bf16x8 a[2][4];
    #pragma unroll
    for (int mt = 0; mt < 2; ++mt)
        #pragma unroll
        for (int ks = 0; ks < 4; ++ks)
            a[mt][ks] = *reinterpret_cast<const bf16x8*>(
                &hb[swz(mt * 16 + cl, ks * 32 + kg * 8)]);
    #pragma unroll
    for (int nt = 0; nt < 8; ++nt) {
        const unsigned short* wrow = WT + (nt * 16 + cl) * KP + kg * 8;
        bf16x8 bf[4];
        #pragma unroll
        for (int ks = 0; ks < 4; ++ks)
            bf[ks] = *reinterpret_cast<const bf16x8*>(wrow + ks * 32);
        const float bv = bp[nt * 16 + cl];
        #pragma unroll
        for (int mt = 0; mt < 2; ++mt) {
            f32x4 acc = {bv, bv, bv, bv};
            #pragma unroll
            for (int ks = 0; ks < 4; ++ks)
                acc = __builtin_amdgcn_mfma_f32_16x16x32_bf16(a[mt][ks], bf[ks], acc, 0, 0, 0);
            #pragma unroll
            for (int j = 0; j < 4; ++j)
                hb[swz(mt * 16 + kg * 4 + j, nt * 16 + cl)] =
                    (short)f2bf(fmaxf(acc[j], 0.f));
        }
    }
}

// ---------------- main kernel: 4 independent waves, ZERO barriers ----------
__global__ __launch_bounds__(256, 4)
void edge_kernel(const float* __restrict__ x, const float* __restrict__ ipos,
                 const float* __restrict__ opos, const int* __restrict__ esrc,
                 const int* __restrict__ edst,
                 const unsigned short* __restrict__ W1T,
                 const unsigned short* __restrict__ W2T,
                 const unsigned short* __restrict__ W3T,
                 const unsigned short* __restrict__ W4T,
                 const float* __restrict__ b1p, const float* __restrict__ b2p,
                 const float* __restrict__ b3p, const float* __restrict__ b4p,
                 float* __restrict__ agg, float* __restrict__ deg)
{
    __shared__ __align__(16) char smem[4][XSS * 16 * 16];  // 9728 B per wave

    const int tid  = threadIdx.x;
    const int wv   = __builtin_amdgcn_readfirstlane(tid >> 6);
    const int lane = tid & 63;
    const int cl   = lane & 15;
    const int kg   = lane >> 4;

    short*  hb  = reinterpret_cast<short*>(smem[wv]);
    float4* xs4 = reinterpret_cast<float4*>(smem[wv]);

    const int tile = blockIdx.x * 4 + wv;
    const int e0   = tile * M;

    // per-lane edge indices (lanes 32-63 duplicate lanes 0-31)
    const int myE  = e0 + (lane & 31);
    const int srcv = esrc[myE];
    const int dstv = edst[myE];
    if (lane < 32) atomicAdd(&deg[dstv], 1.0f);

    // ---- layer 1 as MFMA (K=32 padded, attrs in A-frags from registers) ----
    bf16x8 a1[2];
    #pragma unroll
    for (int mt = 0; mt < 2; ++mt) {
        const int eA = mt * 16 + cl;
        const int s  = __shfl(srcv, eA);
        const int d  = __shfl(dstv, eA);
        bf16x8 v = {0, 0, 0, 0, 0, 0, 0, 0};
        if (kg == 0) {
            v[0] = (short)f2bf(opos[d * 3 + 0]);
            v[1] = (short)f2bf(opos[d * 3 + 1]);
            v[2] = (short)f2bf(opos[d * 3 + 2]);
            v[3] = (short)f2bf(ipos[s * 3 + 0]);
            v[4] = (short)f2bf(ipos[s * 3 + 1]);
            v[5] = (short)f2bf(ipos[s * 3 + 2]);
        }
        a1[mt] = v;
    }
    #pragma unroll
    for (int nt = 0; nt < 8; ++nt) {
        bf16x8 bf = *reinterpret_cast<const bf16x8*>(
            W1T + (nt * 16 + cl) * 32 + kg * 8);
        const float bv = b1p[nt * 16 + cl];
        #pragma unroll
        for (int mt = 0; mt < 2; ++mt) {
            f32x4 acc = {bv, bv, bv, bv};
            acc = __builtin_amdgcn_mfma_f32_16x16x32_bf16(a1[mt], bf, acc, 0, 0, 0);
            #pragma unroll
            for (int j = 0; j < 4; ++j)
                hb[swz(mt * 16 + kg * 4 + j, nt * 16 + cl)] =
                    (short)f2bf(fmaxf(acc[j], 0.f));
        }
    }

    // ---- layers 2, 3 (in-place, wave-private, no barriers) ----
    hidden_layer(W2T, b2p, hb, cl, kg);
    hidden_layer(W3T, b3p, hb, cl, kg);

    // ---- layer 4 A-frags into regs (then hb is dead -> overlay xs) ----
    bf16x8 a4[2][4];
    #pragma unroll
    for (int mt = 0; mt < 2; ++mt)
        #pragma unroll
        for (int ks = 0; ks < 4; ++ks)
            a4[mt][ks] = *reinterpret_cast<const bf16x8*>(
                &hb[swz(mt * 16 + cl, ks * 32 + kg * 8)]);

    // ---- x gather: lane covers edge (lane&31), i-quads {2*(lane>>5)+s} ----
    {
        const int q2 = lane >> 5;
        const int eMy = lane & 31;
        float4 xq[2][4];
        #pragma unroll
        for (int s = 0; s < 2; ++s) {
            const int q = q2 * 2 + s;
            #pragma unroll
            for (int b = 0; b < 4; ++b)
                xq[s][b] = *reinterpret_cast<const float4*>(
                    &x[((size_t)b * NIN_ + srcv) * CI + q * 4]);
        }
        #pragma unroll
        for (int s = 0; s < 2; ++s) {
            const int q = q2 * 2 + s;
            #pragma unroll
            for (int r = 0; r < 4; ++r) {
                float4 v;
                v.x = xq[s][0][r]; v.y = xq[s][1][r];
                v.z = xq[s][2][r]; v.w = xq[s][3][r];
                xs4[(q * 4 + r) * XSS + exmap(eMy)] = v;
            }
        }
    }

    // ---- layer 4 + fused message ----
    float macc[2][16];   // [mt][b*4+j]
    #pragma unroll
    for (int mt = 0; mt < 2; ++mt)
        #pragma unroll
        for (int q = 0; q < 16; ++q) macc[mt][q] = 0.f;

    #pragma unroll 4
    for (int nt = 0; nt < 16; ++nt) {
        const unsigned short* wrow = W4T + (nt * 16 + cl) * KP + kg * 8;
        bf16x8 bf[4];
        #pragma unroll
        for (int ks = 0; ks < 4; ++ks)
            bf[ks] = *reinterpret_cast<const bf16x8*>(wrow + ks * 32);
        const float bv = b4p[nt * 16 + cl];
        #pragma unroll
        for (int mt = 0; mt < 2; ++mt) {
            f32x4 acc = {bv, bv, bv, bv};
            #pragma unroll
            for (int ks = 0; ks < 4; ++ks)
                acc = __builtin_amdgcn_mfma_f32_16x16x32_bf16(a4[mt][ks], bf[ks], acc, 0, 0, 0);
            #pragma unroll
            for (int j = 0; j < 4; ++j) {
                const int e = mt * 16 + kg * 4 + j;
                float4 xv = xs4[nt * XSS + exmap(e)];   // 0-conflict broadcast
                macc[mt][0 * 4 + j] = fmaf(xv.x, acc[j], macc[mt][0 * 4 + j]);
                macc[mt][1 * 4 + j] = fmaf(xv.y, acc[j], macc[mt][1 * 4 + j]);
                macc[mt][2 * 4 + j] = fmaf(xv.z, acc[j], macc[mt][2 * 4 + j]);
                macc[mt][3 * 4 + j] = fmaf(xv.w, acc[j], macc[mt][3 * 4 + j]);
            }
        }
    }

    // ---- scatter ----
    #pragma unroll
    for (int mt = 0; mt < 2; ++mt)
        #pragma unroll
        for (int j = 0; j < 4; ++j) {
            const int e = mt * 16 + kg * 4 + j;
            const int d = __shfl(dstv, e);
            float* p = agg + (size_t)d * (B_ * CO) + cl;
            #pragma unroll
            for (int b = 0; b < 4; ++b)
                atomicAdd(p + b * 16, macc[mt][b * 4 + j]);
        }
}

// out[b][n][o] = agg[n][b][o] / max(deg[n],1) + bias[o]
__global__ __launch_bounds__(256)
void finalize_kernel(const float* __restrict__ agg, const float* __restrict__ deg,
                     const float* __restrict__ bias, float* __restrict__ out)
{
    const int idx = blockIdx.x * 256 + threadIdx.x;
    if (idx >= B_ * NOUT_ * CO) return;
    const int o = idx & 15;
    const int n = (idx >> 4) % NOUT_;
    const int b = idx / (NOUT_ * CO);
    const float d = fmaxf(deg[n], 1.0f);
    out[idx] = agg[(size_t)n * (B_ * CO) + b * CO + o] / d + bias[o];
}

extern "C" void kernel_launch(void* const* d_in, const int* in_sizes, int n_in,
                              void* d_out, int out_size, void* d_ws, size_t ws_size,
                              hipStream_t stream)
{
    const float* x    = (const float*)d_in[0];
    const float* ipos = (const float*)d_in[1];
    const float* opos = (const float*)d_in[2];
    const int*   esrc = (const int*)d_in[3];
    const int*   edst = (const int*)d_in[4];
    const float* w1   = (const float*)d_in[5];
    const float* b1   = (const float*)d_in[6];
    const float* w2   = (const float*)d_in[7];
    const float* b2   = (const float*)d_in[8];
    const float* w3   = (const float*)d_in[9];
    const float* b3   = (const float*)d_in[10];
    const float* w4   = (const float*)d_in[11];
    const float* b4   = (const float*)d_in[12];
    const float* bias = (const float*)d_in[14];

    // Weight scratch in d_out's head (~139 KB); finalize overwrites it.
    char* ob = (char*)d_out;
    unsigned short* W2T = (unsigned short*)(ob);            // 32 KB
    unsigned short* W3T = (unsigned short*)(ob + 32768);    // 32 KB
    unsigned short* W4T = (unsigned short*)(ob + 65536);    // 64 KB
    unsigned short* W1T = (unsigned short*)(ob + 131072);   // 8 KB
    float* b1p = (float*)(ob + 139264);
    float* b2p = (float*)(ob + 139776);
    float* b3p = (float*)(ob + 140288);
    float* b4p = (float*)(ob + 140800);                     // ends 141824 B

    float* agg = (float*)d_ws;
    float* deg = agg + (size_t)NOUT_ * (B_ * CO);

    hipMemsetAsync(d_ws, 0,
                   ((size_t)NOUT_ * (B_ * CO) + NOUT_) * sizeof(float), stream);

    prep_kernel<<<275, 256, 0, stream>>>(w1, w2, w3, w4, b1, b2, b3, b4,
                                         W1T, W2T, W3T, W4T,
                                         b1p, b2p, b3p, b4p);

    edge_kernel<<<E_ / M / 4, 256, 0, stream>>>(
        x, ipos, opos, esrc, edst,
        W1T, W2T, W3T, W4T, b1p, b2p, b3p, b4p, agg, deg);

    const int total = B_ * NOUT_ * CO;
    finalize_kernel<<<(total + 255) / 256, 256, 0, stream>>>(agg, deg, bias,
                                                             (float*)d_out);
}